// Round 3
// baseline (573.092 us; speedup 1.0000x reference)
//
#include <hip/hip_runtime.h>
#include <stdint.h>

#define D_MODEL 1024
#define D_HIDDEN 4096
#define NUM_EXPERTS 8
#define NTOK 4096  // B*T = 2*2048
#define MAXSLOT 40 // sum_e ceil(cnt_e/128) <= 32+7 = 39

typedef __bf16 bf16x8 __attribute__((ext_vector_type(8)));
typedef float floatx4 __attribute__((ext_vector_type(4)));
typedef unsigned int uint2e __attribute__((ext_vector_type(2)));
typedef unsigned int uint4e __attribute__((ext_vector_type(4)));

static __device__ __forceinline__ unsigned short f2bf(float f) {
    union { float f; unsigned int i; } v;
    v.f = f;
    unsigned int i = v.i;
    unsigned int r = (i + 0x7fffu + ((i >> 16) & 1u)) >> 16;  // RNE
    return (unsigned short)r;
}

// async global->LDS, 16B per lane. LDS dest = wave-uniform base + lane*16.
static __device__ __forceinline__ void gl_lds16(const unsigned short* g, unsigned short* l) {
    __builtin_amdgcn_global_load_lds(
        (const __attribute__((address_space(1))) void*)g,
        (__attribute__((address_space(3))) void*)l, 16, 0, 0);
}

// HW transpose read: 16-lane group at tilebase + (lane&15)*8 receives column
// (lane&15) of the [4k][16n] bf16 subtile (4 elems, k-ascending).
#define TRRD(dst, addr, off)                                   \
    asm volatile("ds_read_b64_tr_b16 %0, %1 offset:" #off      \
                 : "=v"(dst) : "v"(addr) : "memory")

static __device__ __forceinline__ bf16x8 pack_tr(uint2e a, uint2e b) {
    uint4e p; p.x = a.x; p.y = a.y; p.z = b.x; p.w = b.y;
    return __builtin_bit_cast(bf16x8, p);
}

// ---------------------------------------------------------------------------
// Fused: blocks 0..2047 = weight fp32->bf16 convert (native layout, pure
// streaming); blocks 2048..3071 = gating (one wave/token) + x->bf16.
// ---------------------------------------------------------------------------
__global__ __launch_bounds__(256) void convgate_kernel(
    const float* __restrict__ x,    // [NTOK][D_MODEL]
    const float* __restrict__ Wg,   // [D_MODEL][NUM_EXPERTS]
    const float* __restrict__ bg,   // [NUM_EXPERTS]
    const float* __restrict__ W1,   // [E][D_MODEL][D_HIDDEN]
    const float* __restrict__ W2,   // [E][D_HIDDEN][D_MODEL]
    int* __restrict__ counts,       // [NUM_EXPERTS] (pre-zeroed)
    int* __restrict__ tlist,        // [NUM_EXPERTS][NTOK]
    float* __restrict__ wgt,        // [NTOK]
    unsigned short* __restrict__ xb, // [NTOK][D_MODEL] bf16
    unsigned short* __restrict__ w1c,// [E][D_MODEL][D_HIDDEN] bf16 native
    unsigned short* __restrict__ w2c)// [E][D_HIDDEN][D_MODEL] bf16 native
{
    const int tid = threadIdx.x;
    if (blockIdx.x < 2048) {
        const int bid = blockIdx.x;
        const float* src = (bid < 1024) ? W1 : W2;
        unsigned short* dst = (bid < 1024) ? w1c : w2c;
        const size_t base = (size_t)(bid & 1023) * 32768 + (size_t)tid * 8;
#pragma unroll
        for (int i = 0; i < 16; i++) {
            size_t idx = base + (size_t)i * 2048;
            float4 v0 = *(const float4*)(src + idx);
            float4 v1 = *(const float4*)(src + idx + 4);
            uint4 o;
            o.x = (unsigned)f2bf(v0.x) | ((unsigned)f2bf(v0.y) << 16);
            o.y = (unsigned)f2bf(v0.z) | ((unsigned)f2bf(v0.w) << 16);
            o.z = (unsigned)f2bf(v1.x) | ((unsigned)f2bf(v1.y) << 16);
            o.w = (unsigned)f2bf(v1.z) | ((unsigned)f2bf(v1.w) << 16);
            *(uint4*)(dst + idx) = o;
        }
        return;
    }

    const int wave = tid >> 6;
    const int lane = tid & 63;
    const int tok = (blockIdx.x - 2048) * 4 + wave;

    float acc[NUM_EXPERTS];
#pragma unroll
    for (int e = 0; e < NUM_EXPERTS; e++) acc[e] = 0.f;

    const float4* xr = (const float4*)(x + (size_t)tok * D_MODEL);
    unsigned int* xbr = (unsigned int*)(xb + (size_t)tok * D_MODEL);

#pragma unroll
    for (int i = 0; i < 4; i++) {
        int d4 = i * 64 + lane;          // float4 index within row (256 total)
        float4 v = xr[d4];
        unsigned int p0 = (unsigned int)f2bf(v.x) | ((unsigned int)f2bf(v.y) << 16);
        unsigned int p1 = (unsigned int)f2bf(v.z) | ((unsigned int)f2bf(v.w) << 16);
        uint2 pk; pk.x = p0; pk.y = p1;
        *(uint2*)&xbr[d4 * 2] = pk;      // 8B/lane coalesced

        float vc[4] = {v.x, v.y, v.z, v.w};
#pragma unroll
        for (int c = 0; c < 4; c++) {
            const float4* wr = (const float4*)(Wg + (size_t)(d4 * 4 + c) * NUM_EXPERTS);
            float4 w0 = wr[0], w1 = wr[1];
            acc[0] += vc[c] * w0.x; acc[1] += vc[c] * w0.y;
            acc[2] += vc[c] * w0.z; acc[3] += vc[c] * w0.w;
            acc[4] += vc[c] * w1.x; acc[5] += vc[c] * w1.y;
            acc[6] += vc[c] * w1.z; acc[7] += vc[c] * w1.w;
        }
    }
#pragma unroll
    for (int e = 0; e < NUM_EXPERTS; e++) {
        float v = acc[e];
#pragma unroll
        for (int off = 32; off > 0; off >>= 1) v += __shfl_xor(v, off, 64);
        acc[e] = v;
    }
    if (lane == 0) {
        float lg[NUM_EXPERTS];
#pragma unroll
        for (int e = 0; e < NUM_EXPERTS; e++) lg[e] = acc[e] + bg[e];
        int amax = 0;
        float m = lg[0];
#pragma unroll
        for (int e = 1; e < NUM_EXPERTS; e++) {
            if (lg[e] > m) { m = lg[e]; amax = e; }  // first-index-wins
        }
        float s = 0.f;
#pragma unroll
        for (int e = 0; e < NUM_EXPERTS; e++) s += __expf(lg[e] - m);
        wgt[tok] = 1.0f / s;
        int pos = atomicAdd(&counts[amax], 1);
        tlist[amax * NTOK + pos] = tok;
    }
}

// ---------------------------------------------------------------------------
// tile-slot -> (expert, m_tile, count), 128-row granularity.
// ---------------------------------------------------------------------------
__device__ __forceinline__ bool slot_to_expert(const int* counts, int slot,
                                               int& e_out, int& mt_out, int& cnt_out) {
    int cum = 0;
    for (int i = 0; i < NUM_EXPERTS; i++) {
        int c = counts[i];
        int tt = (c + 127) >> 7;
        if (slot < cum + tt) {
            e_out = i; mt_out = slot - cum; cnt_out = c;
            return true;
        }
        cum += tt;
    }
    return false;
}

// ---------------------------------------------------------------------------
// FFN1: 128x128 tile, BK=32, 4 waves, 2-phase dbuf gl_lds staging.
// A (tokens): [128][32] XOR-swizzled, ds_read_b128 (proven r2 structure).
// B (weights): NATIVE [k][n] staged subtiled [nb][32k][16n];
//              consumed via ds_read_b64_tr_b16 (HW transpose read).
// ---------------------------------------------------------------------------
__global__ __launch_bounds__(256) void ffn1_kernel(
    const unsigned short* __restrict__ xb,   // [NTOK][D_MODEL] bf16
    const unsigned short* __restrict__ w1c,  // [E][D_MODEL][D_HIDDEN] bf16 native
    const float* __restrict__ b1,            // [E][D_HIDDEN]
    const int* __restrict__ counts,
    const int* __restrict__ tlist,
    unsigned short* __restrict__ h)          // [NTOK][D_HIDDEN] bf16
{
    int e, mt, cnt;
    if (!slot_to_expert(counts, blockIdx.y, e, mt, cnt)) return;
    const int n0 = blockIdx.x * 128;

    __shared__ __align__(16) unsigned short As[2][4096];
    __shared__ __align__(16) unsigned short Bs[2][4096];
    __shared__ int toks[128];

    const int tid = threadIdx.x;
    if (tid < 128) {
        int r = mt * 128 + tid;
        toks[tid] = (r < cnt) ? tlist[e * NTOK + r] : -1;
    }
    __syncthreads();

    const int wave = tid >> 6, lane = tid & 63;
    const int quad = lane >> 4, lm = lane & 15;
    const int mo = (wave & 1) * 64, no = (wave >> 1) * 64;

    // A staging geometry (unchanged from r2, verified)
    const int srow = wave * 16 + (lane >> 2);
    const int kq = (lane & 3) ^ ((lane >> 3) & 3);
    int tA0 = toks[srow], tA1 = toks[64 + srow];
    const unsigned short* a0p = xb + (size_t)(tA0 < 0 ? 0 : tA0) * D_MODEL + kq * 8;
    const unsigned short* a1p = xb + (size_t)(tA1 < 0 ? 0 : tA1) * D_MODEL + kq * 8;

    // B staging: lane l fetches W[k0 + (l>>1)][n0 + nb*16 + (l&1)*8], 16B.
    // Linear LDS write order == [nb][32k][16n] subtiling.
    const unsigned short* w1e = w1c + (size_t)e * D_MODEL * D_HIDDEN;
    const unsigned short* bsrc = w1e + (size_t)(lane >> 1) * D_HIDDEN + n0 + (lane & 1) * 8;

    const int fq = (quad ^ ((lm >> 1) & 3)) * 8;   // swizzled A fragment k-offset

    // tr-read per-lane address: tile base (per group g=quad) + (lane&15)*8 B
    const unsigned trb = ((unsigned)(lane >> 4) << 8) | ((unsigned)(lane & 15) << 3);
    const unsigned adB0 = (unsigned)(uintptr_t)&Bs[0][0] + (unsigned)((wave >> 1) * 4096) + trb;
    const unsigned adB1 = (unsigned)(uintptr_t)&Bs[1][0] + (unsigned)((wave >> 1) * 4096) + trb;

    floatx4 acc[4][4];
#pragma unroll
    for (int i = 0; i < 4; i++)
#pragma unroll
        for (int j = 0; j < 4; j++) acc[i][j] = (floatx4){0.f, 0.f, 0.f, 0.f};

#define FFN1_STAGE(b, k0)                                          \
    do {                                                           \
        gl_lds16(a0p + (k0), As[b] + wave * 512);                  \
        gl_lds16(a1p + (k0), As[b] + 2048 + wave * 512);           \
        const unsigned short* bs_ = bsrc + (size_t)(k0) * D_HIDDEN;\
        gl_lds16(bs_ + wave * 16, Bs[b] + wave * 512);             \
        gl_lds16(bs_ + (wave + 4) * 16, Bs[b] + 2048 + wave * 512);\
    } while (0)

#define FFN1_COMPUTE(b, adB)                                                  \
    do {                                                                      \
        bf16x8 af[4];                                                         \
        _Pragma("unroll")                                                     \
        for (int i = 0; i < 4; i++)                                           \
            af[i] = *(const bf16x8*)(As[b] + (mo + i * 16 + lm) * 32 + fq);   \
        uint2e t0, t1, t2, t3, t4, t5, t6, t7;                                \
        TRRD(t0, adB, 0);    TRRD(t1, adB, 128);                              \
        TRRD(t2, adB, 1024); TRRD(t3, adB, 1152);                             \
        TRRD(t4, adB, 2048); TRRD(t5, adB, 2176);                             \
        TRRD(t6, adB, 3072); TRRD(t7, adB, 3200);                             \
        asm volatile("s_waitcnt lgkmcnt(0)" ::: "memory");                    \
        __builtin_amdgcn_sched_barrier(0);                                    \
        bf16x8 bfr[4];                                                        \
        bfr[0] = pack_tr(t0, t1); bfr[1] = pack_tr(t2, t3);                   \
        bfr[2] = pack_tr(t4, t5); bfr[3] = pack_tr(t6, t7);                   \
        _Pragma("unroll")                                                     \
        for (int mi = 0; mi < 4; mi++)                                        \
            _Pragma("unroll")                                                 \
            for (int ni = 0; ni < 4; ni++)                                    \
                acc[mi][ni] = __builtin_amdgcn_mfma_f32_16x16x32_bf16(        \
                    af[mi], bfr[ni], acc[mi][ni], 0, 0, 0);                   \
    } while (0)

    FFN1_STAGE(0, 0);
    __syncthreads();   // drains vmcnt(0): buf0 ready
    int cur = 0;
    for (int k0 = 32; k0 < D_MODEL; k0 += 32) {
        FFN1_STAGE(cur ^ 1, k0);   // issue next-tile loads BEFORE compute
        unsigned adB = cur ? adB1 : adB0;
        FFN1_COMPUTE(cur, adB);
        __syncthreads();
        cur ^= 1;
    }
    {
        unsigned adB = cur ? adB1 : adB0;
        FFN1_COMPUTE(cur, adB);
    }

    const float* b1e = b1 + (size_t)e * D_HIDDEN;
#pragma unroll
    for (int ni = 0; ni < 4; ni++) {
        int n = n0 + no + ni * 16 + lm;
        float bias = b1e[n];
#pragma unroll
        for (int mi = 0; mi < 4; mi++)
#pragma unroll
            for (int r = 0; r < 4; r++) {
                int m = mo + mi * 16 + quad * 4 + r;
                int tk = toks[m];
                if (tk >= 0) {
                    float z = acc[mi][ni][r] + bias;
                    h[(size_t)tk * D_HIDDEN + n] = f2bf(z / (1.f + __expf(-z)));
                }
            }
    }
}

// ---------------------------------------------------------------------------
// FFN2: 128x64 tile, K=4096 full (no split-K, no atomics). Same B-native +
// tr-read structure; A = h rows.
// ---------------------------------------------------------------------------
__global__ __launch_bounds__(256) void ffn2_kernel(
    const unsigned short* __restrict__ h,    // [NTOK][D_HIDDEN] bf16
    const unsigned short* __restrict__ w2c,  // [E][D_HIDDEN][D_MODEL] bf16 native
    const float* __restrict__ b2,            // [E][D_MODEL]
    const int* __restrict__ counts,
    const int* __restrict__ tlist,
    const float* __restrict__ wgt,
    float* __restrict__ out)                 // [NTOK][D_MODEL] fp32
{
    int e, mt, cnt;
    if (!slot_to_expert(counts, blockIdx.y, e, mt, cnt)) return;
    const int n0 = blockIdx.x * 64;

    __shared__ __align__(16) unsigned short As[2][4096];
    __shared__ __align__(16) unsigned short Bs[2][2048];
    __shared__ int toks[128];

    const int tid = threadIdx.x;
    if (tid < 128) {
        int r = mt * 128 + tid;
        toks[tid] = (r < cnt) ? tlist[e * NTOK + r] : -1;
    }
    __syncthreads();

    const int wave = tid >> 6, lane = tid & 63;
    const int quad = lane >> 4, lm = lane & 15;
    const int mo = (wave & 1) * 64, no = (wave >> 1) * 32;

    const int srow = wave * 16 + (lane >> 2);
    const int kq = (lane & 3) ^ ((lane >> 3) & 3);
    int tA0 = toks[srow], tA1 = toks[64 + srow];
    const unsigned short* a0p = h + (size_t)(tA0 < 0 ? 0 : tA0) * D_HIDDEN + kq * 8;
    const unsigned short* a1p = h + (size_t)(tA1 < 0 ? 0 : tA1) * D_HIDDEN + kq * 8;

    const unsigned short* w2e = w2c + (size_t)e * D_MODEL * D_HIDDEN;
    const unsigned short* bsrc = w2e + (size_t)(lane >> 1) * D_MODEL + n0 + (lane & 1) * 8;

    const int fq = (quad ^ ((lm >> 1) & 3)) * 8;

    const unsigned trb = ((unsigned)(lane >> 4) << 8) | ((unsigned)(lane & 15) << 3);
    const unsigned adB0 = (unsigned)(uintptr_t)&Bs[0][0] + (unsigned)((wave >> 1) * 2048) + trb;
    const unsigned adB1 = (unsigned)(uintptr_t)&Bs[1][0] + (unsigned)((wave >> 1) * 2048) + trb;

    floatx4 acc[4][2];
#pragma unroll
    for (int i = 0; i < 4; i++)
#pragma unroll
        for (int j = 0; j < 2; j++) acc[i][j] = (floatx4){0.f, 0.f, 0.f, 0.f};

#define FFN2_STAGE(b, k0)                                          \
    do {                                                           \
        gl_lds16(a0p + (k0), As[b] + wave * 512);                  \
        gl_lds16(a1p + (k0), As[b] + 2048 + wave * 512);           \
        gl_lds16(bsrc + (size_t)(k0) * D_MODEL + wave * 16,        \
                 Bs[b] + wave * 512);                              \
    } while (0)

#define FFN2_COMPUTE(b, adB)                                                  \
    do {                                                                      \
        bf16x8 af[4];                                                         \
        _Pragma("unroll")                                                     \
        for (int i = 0; i < 4; i++)                                           \
            af[i] = *(const bf16x8*)(As[b] + (mo + i * 16 + lm) * 32 + fq);   \
        uint2e t0, t1, t2, t3;                                                \
        TRRD(t0, adB, 0);    TRRD(t1, adB, 128);                              \
        TRRD(t2, adB, 1024); TRRD(t3, adB, 1152);                             \
        asm volatile("s_waitcnt lgkmcnt(0)" ::: "memory");                    \
        __builtin_amdgcn_sched_barrier(0);                                    \
        bf16x8 bfr[2];                                                        \
        bfr[0] = pack_tr(t0, t1); bfr[1] = pack_tr(t2, t3);                   \
        _Pragma("unroll")                                                     \
        for (int mi = 0; mi < 4; mi++)                                        \
            _Pragma("unroll")                                                 \
            for (int ni = 0; ni < 2; ni++)                                    \
                acc[mi][ni] = __builtin_amdgcn_mfma_f32_16x16x32_bf16(        \
                    af[mi], bfr[ni], acc[mi][ni], 0, 0, 0);                   \
    } while (0)

    FFN2_STAGE(0, 0);
    __syncthreads();
    int cur = 0;
    for (int k0 = 32; k0 < D_HIDDEN; k0 += 32) {
        FFN2_STAGE(cur ^ 1, k0);
        unsigned adB = cur ? adB1 : adB0;
        FFN2_COMPUTE(cur, adB);
        __syncthreads();
        cur ^= 1;
    }
    {
        unsigned adB = cur ? adB1 : adB0;
        FFN2_COMPUTE(cur, adB);
    }

    const float* b2e = b2 + (size_t)e * D_MODEL;
#pragma unroll
    for (int ni = 0; ni < 2; ni++) {
        int n = n0 + no + ni * 16 + lm;
        float bias = b2e[n];
#pragma unroll
        for (int mi = 0; mi < 4; mi++)
#pragma unroll
            for (int r = 0; r < 4; r++) {
                int m = mo + mi * 16 + quad * 4 + r;
                int tk = toks[m];
                if (tk >= 0) {
                    out[(size_t)tk * D_MODEL + n] = (acc[mi][ni][r] + bias) * wgt[tk];
                }
            }
    }
}

// ---------------------------------------------------------------------------
extern "C" void kernel_launch(void* const* d_in, const int* in_sizes, int n_in,
                              void* d_out, int out_size, void* d_ws, size_t ws_size,
                              hipStream_t stream) {
    const float* x  = (const float*)d_in[0];
    const float* Wg = (const float*)d_in[1];
    const float* bg = (const float*)d_in[2];
    const float* W1 = (const float*)d_in[3];
    const float* b1 = (const float*)d_in[4];
    const float* W2 = (const float*)d_in[5];
    const float* b2 = (const float*)d_in[6];
    float* out = (float*)d_out;

    char* ws = (char*)d_ws;
    int*   counts = (int*)ws;                               // 32 B
    float* wgt    = (float*)(ws + 1024);                    // 16 KB
    int*   tlist  = (int*)(ws + 32768);                     // 128 KB
    unsigned short* xb   = (unsigned short*)(ws + 262144);  // 8.39 MB bf16
    unsigned short* hbuf = (unsigned short*)(ws + 8650752); // 33.55 MB bf16
    unsigned short* w1c  = (unsigned short*)(ws + 42205184);  // 67.1 MB bf16 native
    unsigned short* w2c  = (unsigned short*)(ws + 109314048); // 67.1 MB bf16 native
    // total workspace: 176,422,912 B

    hipMemsetAsync(counts, 0, NUM_EXPERTS * sizeof(int), stream);

    convgate_kernel<<<3072, 256, 0, stream>>>(x, Wg, bg, W1, W2,
                                              counts, tlist, wgt, xb, w1c, w2c);
    ffn1_kernel<<<dim3(D_HIDDEN / 128, MAXSLOT), 256, 0, stream>>>(
        xb, w1c, b1, counts, tlist, hbuf);
    ffn2_kernel<<<dim3(D_MODEL / 64, MAXSLOT), 256, 0, stream>>>(
        hbuf, w2c, b2, counts, tlist, wgt, out);
}

// Round 5
// 563.765 us; speedup vs baseline: 1.0165x; 1.0165x over previous
//
#include <hip/hip_runtime.h>
#include <stdint.h>

#define D_MODEL 1024
#define D_HIDDEN 4096
#define NUM_EXPERTS 8
#define NTOK 4096   // B*T = 2*2048
#define MAXSLOT1 24 // ffn1: sum_e ceil(cnt_e/256) <= 16+8
#define MAXSLOT2 40 // ffn2: sum_e ceil(cnt_e/128) <= 32+8

typedef __bf16 bf16x8 __attribute__((ext_vector_type(8)));
typedef float floatx4 __attribute__((ext_vector_type(4)));
typedef unsigned int uint2e __attribute__((ext_vector_type(2)));
typedef unsigned int uint4e __attribute__((ext_vector_type(4)));

static __device__ __forceinline__ unsigned short f2bf(float f) {
    union { float f; unsigned int i; } v;
    v.f = f;
    unsigned int i = v.i;
    unsigned int r = (i + 0x7fffu + ((i >> 16) & 1u)) >> 16;  // RNE
    return (unsigned short)r;
}

// async global->LDS, 16B per lane. LDS dest operand is the WAVE-UNIFORM base;
// HW adds lane*16 B (m104/m108).
static __device__ __forceinline__ void gl_lds16(const unsigned short* g, unsigned short* l) {
    __builtin_amdgcn_global_load_lds(
        (const __attribute__((address_space(1))) void*)g,
        (__attribute__((address_space(3))) void*)l, 16, 0, 0);
}

// HW transpose read (verified in r3): lane with byte addr A receives column
// (A&127)>>3 of the 128-B-aligned [4k][16n] bf16 tile containing A (4 elems,
// k-ascending). offset:N is additive.
#define TRRD(dst, addr, off)                                   \
    asm volatile("ds_read_b64_tr_b16 %0, %1 offset:" #off      \
                 : "=v"(dst) : "v"(addr) : "memory")

static __device__ __forceinline__ bf16x8 pack_tr(uint2e a, uint2e b) {
    uint4e p; p.x = a.x; p.y = a.y; p.z = b.x; p.w = b.y;
    return __builtin_bit_cast(bf16x8, p);
}

// ---------------------------------------------------------------------------
// Fused: blocks 0..8191 = weight fp32->bf16 convert (native layout, batched
// ILP-4 loads then stores); blocks 8192..9215 = gating (one wave/token).
// ---------------------------------------------------------------------------
__global__ __launch_bounds__(256) void convgate_kernel(
    const float* __restrict__ x,
    const float* __restrict__ Wg,
    const float* __restrict__ bg,
    const float* __restrict__ W1,
    const float* __restrict__ W2,
    int* __restrict__ counts,
    int* __restrict__ tlist,
    float* __restrict__ wgt,
    unsigned short* __restrict__ xb,
    unsigned short* __restrict__ w1c,  // [E][D_MODEL][D_HIDDEN] bf16 native
    unsigned short* __restrict__ w2c)  // [E][D_HIDDEN][D_MODEL] bf16 native
{
    const int tid = threadIdx.x;
    if (blockIdx.x < 8192) {
        const int half = blockIdx.x >> 12;  // 0: W1, 1: W2
        const float* src = half ? W2 : W1;
        unsigned short* dst = half ? w2c : w1c;
        const size_t c0 = ((size_t)(blockIdx.x & 4095) * 256 + tid) * 8;
        float4 v[8];
#pragma unroll
        for (int q = 0; q < 4; ++q) {
            const float* s = src + c0 + (size_t)q * 8388608;
            v[q * 2]     = *(const float4*)(s);
            v[q * 2 + 1] = *(const float4*)(s + 4);
        }
#pragma unroll
        for (int q = 0; q < 4; ++q) {
            uint4 o;
            o.x = (unsigned)f2bf(v[q*2].x)   | ((unsigned)f2bf(v[q*2].y) << 16);
            o.y = (unsigned)f2bf(v[q*2].z)   | ((unsigned)f2bf(v[q*2].w) << 16);
            o.z = (unsigned)f2bf(v[q*2+1].x) | ((unsigned)f2bf(v[q*2+1].y) << 16);
            o.w = (unsigned)f2bf(v[q*2+1].z) | ((unsigned)f2bf(v[q*2+1].w) << 16);
            *(uint4*)(dst + c0 + (size_t)q * 8388608) = o;
        }
        return;
    }

    const int wave = tid >> 6;
    const int lane = tid & 63;
    const int tok = (blockIdx.x - 8192) * 4 + wave;

    float acc[NUM_EXPERTS];
#pragma unroll
    for (int e = 0; e < NUM_EXPERTS; e++) acc[e] = 0.f;

    const float4* xr = (const float4*)(x + (size_t)tok * D_MODEL);
    unsigned int* xbr = (unsigned int*)(xb + (size_t)tok * D_MODEL);

#pragma unroll
    for (int i = 0; i < 4; i++) {
        int d4 = i * 64 + lane;
        float4 v = xr[d4];
        unsigned int p0 = (unsigned int)f2bf(v.x) | ((unsigned int)f2bf(v.y) << 16);
        unsigned int p1 = (unsigned int)f2bf(v.z) | ((unsigned int)f2bf(v.w) << 16);
        uint2 pk; pk.x = p0; pk.y = p1;
        *(uint2*)&xbr[d4 * 2] = pk;

        float vc[4] = {v.x, v.y, v.z, v.w};
#pragma unroll
        for (int c = 0; c < 4; c++) {
            const float4* wr = (const float4*)(Wg + (size_t)(d4 * 4 + c) * NUM_EXPERTS);
            float4 w0 = wr[0], w1 = wr[1];
            acc[0] += vc[c] * w0.x; acc[1] += vc[c] * w0.y;
            acc[2] += vc[c] * w0.z; acc[3] += vc[c] * w0.w;
            acc[4] += vc[c] * w1.x; acc[5] += vc[c] * w1.y;
            acc[6] += vc[c] * w1.z; acc[7] += vc[c] * w1.w;
        }
    }
#pragma unroll
    for (int e = 0; e < NUM_EXPERTS; e++) {
        float v = acc[e];
#pragma unroll
        for (int off = 32; off > 0; off >>= 1) v += __shfl_xor(v, off, 64);
        acc[e] = v;
    }
    if (lane == 0) {
        float lg[NUM_EXPERTS];
#pragma unroll
        for (int e = 0; e < NUM_EXPERTS; e++) lg[e] = acc[e] + bg[e];
        int amax = 0;
        float m = lg[0];
#pragma unroll
        for (int e = 1; e < NUM_EXPERTS; e++) {
            if (lg[e] > m) { m = lg[e]; amax = e; }  // first-index-wins
        }
        float s = 0.f;
#pragma unroll
        for (int e = 0; e < NUM_EXPERTS; e++) s += __expf(lg[e] - m);
        wgt[tok] = 1.0f / s;
        int pos = atomicAdd(&counts[amax], 1);
        tlist[amax * NTOK + pos] = tok;
    }
}

// ---------------------------------------------------------------------------
// tile-slot -> (expert, m_tile, count); tile = 1<<shift rows.
// ---------------------------------------------------------------------------
__device__ __forceinline__ bool slot_to_expert(const int* counts, int slot, int shift,
                                               int& e_out, int& mt_out, int& cnt_out) {
    int cum = 0;
    for (int i = 0; i < NUM_EXPERTS; i++) {
        int c = counts[i];
        int tt = (c + (1 << shift) - 1) >> shift;
        if (slot < cum + tt) {
            e_out = i; mt_out = slot - cum; cnt_out = c;
            return true;
        }
        cum += tt;
    }
    return false;
}

// ---------------------------------------------------------------------------
// FFN1: 256x256 tile, BK=64, 8 waves (2M x 4N). Proven r2 sync skeleton:
// STAGE(next buf) -> COMPUTE(cur) -> __syncthreads (compiler drains vmcnt).
// A: [4 sect][64 rows][8 slots x 8] with slot = granule ^ (row&7); b128 reads.
// B: native [k][n] staged [16 nb][64k][16n]; ds_read_b64_tr_b16 consume.
// LDS: 2*32KB (A) + 2*32KB (B) + 1KB toks = 129 KB -> 1 block/CU.
// ---------------------------------------------------------------------------
__global__ __launch_bounds__(512, 2) void ffn1_kernel(
    const unsigned short* __restrict__ xb,
    const unsigned short* __restrict__ w1c,
    const float* __restrict__ b1,
    const int* __restrict__ counts,
    const int* __restrict__ tlist,
    unsigned short* __restrict__ h)
{
    int e, mt, cnt;
    if (!slot_to_expert(counts, blockIdx.y, 8, e, mt, cnt)) return;
    const int n0 = blockIdx.x * 256;

    __shared__ __align__(16) unsigned short Al[2][256 * 64];
    __shared__ __align__(16) unsigned short Bl[2][256 * 64];
    __shared__ int toks[256];

    const int tid = threadIdx.x;
    if (tid < 256) {
        int r = mt * 256 + tid;
        toks[tid] = (r < cnt) ? tlist[e * NTOK + r] : -1;
    }
    __syncthreads();

    const int wave = tid >> 6, lane = tid & 63;
    const int quad = lane >> 4, lm = lane & 15;
    const int mo = (wave >> 2) * 128, wc = wave & 3;
    const int no = wc * 64;

    // ---- staging sources (per-thread, loop-invariant) ----
    const unsigned short* w1e = w1c + (size_t)e * D_MODEL * D_HIDDEN;
    const int ag = ((tid & 7) ^ ((tid >> 3) & 7)) * 8;  // pre-swizzled A granule
    const unsigned short* asrc[4];
#pragma unroll
    for (int j = 0; j < 4; ++j) {
        int m = j * 64 + (tid >> 3);
        int tk = toks[m];
        asrc[j] = xb + (size_t)(tk < 0 ? 0 : tk) * D_MODEL + ag;
    }
    const int bk = (tid >> 1) & 63, bn8 = (tid & 1) * 8;
    const unsigned short* bsrc[4];
#pragma unroll
    for (int j = 0; j < 4; ++j) {
        int nb = j * 4 + (tid >> 7);
        bsrc[j] = w1e + (size_t)bk * D_HIDDEN + n0 + nb * 16 + bn8;
    }

    // wave-uniform LDS dest bases; HW adds lane*16B -> thread tid lands at tid*8 shorts
#define F1_STAGE(p, k0)                                                  \
    do {                                                                 \
        _Pragma("unroll")                                                \
        for (int j = 0; j < 4; ++j)                                      \
            gl_lds16(asrc[j] + (k0), &Al[p][j * 4096 + wave * 512]);     \
        _Pragma("unroll")                                                \
        for (int j = 0; j < 4; ++j)                                      \
            gl_lds16(bsrc[j] + (size_t)(k0) * D_HIDDEN,                  \
                     &Bl[p][j * 4096 + wave * 512]);                     \
    } while (0)

#define F1_COMPUTE(p)                                                         \
    do {                                                                      \
        const unsigned short* Ab = &Al[p][0];                                 \
        const unsigned bvB = (unsigned)(uintptr_t)&Bl[p][0]                   \
                           + (unsigned)(wc * 8192 + quad * 256 + lm * 8);     \
        _Pragma("unroll")                                                     \
        for (int s = 0; s < 2; ++s) {                                         \
            bf16x8 af[8];                                                     \
            const int gsw = ((s * 4 + quad) ^ (lm & 7)) * 8;                  \
            _Pragma("unroll")                                                 \
            for (int i = 0; i < 8; ++i)                                       \
                af[i] = *(const bf16x8*)(Ab + (mo + i * 16 + lm) * 64 + gsw); \
            uint2e t0, t1, t2, t3, t4, t5, t6, t7;                            \
            const unsigned vs = bvB + s * 1024;                               \
            unsigned v0 = vs, v1 = vs + 2048, v2 = vs + 4096, v3 = vs + 6144; \
            TRRD(t0, v0, 0); TRRD(t1, v0, 128);                               \
            TRRD(t2, v1, 0); TRRD(t3, v1, 128);                               \
            TRRD(t4, v2, 0); TRRD(t5, v2, 128);                               \
            TRRD(t6, v3, 0); TRRD(t7, v3, 128);                               \
            asm volatile("s_waitcnt lgkmcnt(0)" ::: "memory");                \
            __builtin_amdgcn_sched_barrier(0);                                \
            bf16x8 bf[4];                                                     \
            bf[0] = pack_tr(t0, t1); bf[1] = pack_tr(t2, t3);                 \
            bf[2] = pack_tr(t4, t5); bf[3] = pack_tr(t6, t7);                 \
            _Pragma("unroll")                                                 \
            for (int i = 0; i < 8; ++i)                                       \
                _Pragma("unroll")                                             \
                for (int j = 0; j < 4; ++j)                                   \
                    acc[i][j] = __builtin_amdgcn_mfma_f32_16x16x32_bf16(      \
                        af[i], bf[j], acc[i][j], 0, 0, 0);                    \
        }                                                                     \
    } while (0)

    floatx4 acc[8][4];
#pragma unroll
    for (int i = 0; i < 8; i++)
#pragma unroll
        for (int j = 0; j < 4; j++) acc[i][j] = (floatx4){0.f, 0.f, 0.f, 0.f};

    const int NT = D_MODEL / 64;  // 16
    F1_STAGE(0, 0);
    __syncthreads();              // buf0 ready (barrier drains vmcnt)
    int cur = 0;
    for (int kt = 1; kt < NT; ++kt) {
        F1_STAGE(cur ^ 1, kt * 64);   // issue next-tile loads BEFORE compute
        F1_COMPUTE(cur);
        __syncthreads();              // next buf ready; all reads of cur done
        cur ^= 1;
    }
    F1_COMPUTE(cur);

    const float* b1e = b1 + (size_t)e * D_HIDDEN;
#pragma unroll
    for (int ni = 0; ni < 4; ++ni) {
        int n = n0 + no + ni * 16 + lm;
        float bias = b1e[n];
#pragma unroll
        for (int mi = 0; mi < 8; ++mi)
#pragma unroll
            for (int r = 0; r < 4; ++r) {
                int m = mo + mi * 16 + quad * 4 + r;
                int tk = toks[m];
                if (tk >= 0) {
                    float z = acc[mi][ni][r] + bias;
                    h[(size_t)tk * D_HIDDEN + n] = f2bf(z / (1.f + __expf(-z)));
                }
            }
    }
}

// ---------------------------------------------------------------------------
// FFN2: 128x128 tile, BK=64, 4 waves (2M x 2N), K=4096. Same skeleton.
// LDS 64.5 KB -> 2 blocks/CU (cross-block overlap hides the barrier drain).
// No split-K, no atomics (top-1 covers each out element exactly once).
// ---------------------------------------------------------------------------
__global__ __launch_bounds__(256, 2) void ffn2_kernel(
    const unsigned short* __restrict__ h,
    const unsigned short* __restrict__ w2c,
    const float* __restrict__ b2,
    const int* __restrict__ counts,
    const int* __restrict__ tlist,
    const float* __restrict__ wgt,
    float* __restrict__ out)
{
    int e, mt, cnt;
    if (!slot_to_expert(counts, blockIdx.y, 7, e, mt, cnt)) return;
    const int n0 = blockIdx.x * 128;

    __shared__ __align__(16) unsigned short Al[2][128 * 64];
    __shared__ __align__(16) unsigned short Bl[2][128 * 64];
    __shared__ int toks[128];

    const int tid = threadIdx.x;
    if (tid < 128) {
        int r = mt * 128 + tid;
        toks[tid] = (r < cnt) ? tlist[e * NTOK + r] : -1;
    }
    __syncthreads();

    const int wave = tid >> 6, lane = tid & 63;
    const int quad = lane >> 4, lm = lane & 15;
    const int mo = (wave & 1) * 64, wc = wave >> 1;
    const int no = wc * 64;

    const unsigned short* w2e = w2c + (size_t)e * D_MODEL * D_HIDDEN;
    const int ag = ((tid & 7) ^ ((tid >> 3) & 7)) * 8;
    const unsigned short* asrc[4];
#pragma unroll
    for (int j = 0; j < 4; ++j) {
        int m = j * 32 + (tid >> 3);
        int tk = toks[m];
        asrc[j] = h + (size_t)(tk < 0 ? 0 : tk) * D_HIDDEN + ag;
    }
    const int bk = (tid >> 1) & 63, bn8 = (tid & 1) * 8;
    const unsigned short* bsrc[4];
#pragma unroll
    for (int j = 0; j < 4; ++j) {
        int nb = j * 2 + (tid >> 7);
        bsrc[j] = w2e + (size_t)bk * D_MODEL + n0 + nb * 16 + bn8;
    }

#define F2_STAGE(p, k0)                                                  \
    do {                                                                 \
        _Pragma("unroll")                                                \
        for (int j = 0; j < 4; ++j)                                      \
            gl_lds16(asrc[j] + (k0), &Al[p][j * 2048 + wave * 512]);     \
        _Pragma("unroll")                                                \
        for (int j = 0; j < 4; ++j)                                      \
            gl_lds16(bsrc[j] + (size_t)(k0) * D_MODEL,                   \
                     &Bl[p][j * 2048 + wave * 512]);                     \
    } while (0)

#define F2_COMPUTE(p)                                                         \
    do {                                                                      \
        const unsigned short* Ab = &Al[p][0];                                 \
        const unsigned bvB = (unsigned)(uintptr_t)&Bl[p][0]                   \
                           + (unsigned)(wc * 8192 + quad * 256 + lm * 8);     \
        _Pragma("unroll")                                                     \
        for (int s = 0; s < 2; ++s) {                                         \
            bf16x8 af[4];                                                     \
            const int gsw = ((s * 4 + quad) ^ (lm & 7)) * 8;                  \
            _Pragma("unroll")                                                 \
            for (int i = 0; i < 4; ++i)                                       \
                af[i] = *(const bf16x8*)(Ab + (mo + i * 16 + lm) * 64 + gsw); \
            uint2e t0, t1, t2, t3, t4, t5, t6, t7;                            \
            const unsigned vs = bvB + s * 1024;                               \
            unsigned v0 = vs, v1 = vs + 2048, v2 = vs + 4096, v3 = vs + 6144; \
            TRRD(t0, v0, 0); TRRD(t1, v0, 128);                               \
            TRRD(t2, v1, 0); TRRD(t3, v1, 128);                               \
            TRRD(t4, v2, 0); TRRD(t5, v2, 128);                               \
            TRRD(t6, v3, 0); TRRD(t7, v3, 128);                               \
            asm volatile("s_waitcnt lgkmcnt(0)" ::: "memory");                \
            __builtin_amdgcn_sched_barrier(0);                                \
            bf16x8 bf[4];                                                     \
            bf[0] = pack_tr(t0, t1); bf[1] = pack_tr(t2, t3);                 \
            bf[2] = pack_tr(t4, t5); bf[3] = pack_tr(t6, t7);                 \
            _Pragma("unroll")                                                 \
            for (int i = 0; i < 4; ++i)                                       \
                _Pragma("unroll")                                             \
                for (int j = 0; j < 4; ++j)                                   \
                    acc[i][j] = __builtin_amdgcn_mfma_f32_16x16x32_bf16(      \
                        af[i], bf[j], acc[i][j], 0, 0, 0);                    \
        }                                                                     \
    } while (0)

    floatx4 acc[4][4];
#pragma unroll
    for (int i = 0; i < 4; i++)
#pragma unroll
        for (int j = 0; j < 4; j++) acc[i][j] = (floatx4){0.f, 0.f, 0.f, 0.f};

    const int NT = D_HIDDEN / 64;  // 64
    F2_STAGE(0, 0);
    __syncthreads();
    int cur = 0;
    for (int kt = 1; kt < NT; ++kt) {
        F2_STAGE(cur ^ 1, kt * 64);
        F2_COMPUTE(cur);
        __syncthreads();
        cur ^= 1;
    }
    F2_COMPUTE(cur);

    const float* b2e = b2 + (size_t)e * D_MODEL;
#pragma unroll
    for (int ni = 0; ni < 4; ++ni) {
        int n = n0 + no + ni * 16 + lm;
        float bias = b2e[n];
#pragma unroll
        for (int mi = 0; mi < 4; ++mi)
#pragma unroll
            for (int r = 0; r < 4; ++r) {
                int m = mo + mi * 16 + quad * 4 + r;
                int tk = toks[m];
                if (tk >= 0) {
                    out[(size_t)tk * D_MODEL + n] = (acc[mi][ni][r] + bias) * wgt[tk];
                }
            }
    }
}

// ---------------------------------------------------------------------------
extern "C" void kernel_launch(void* const* d_in, const int* in_sizes, int n_in,
                              void* d_out, int out_size, void* d_ws, size_t ws_size,
                              hipStream_t stream) {
    const float* x  = (const float*)d_in[0];
    const float* Wg = (const float*)d_in[1];
    const float* bg = (const float*)d_in[2];
    const float* W1 = (const float*)d_in[3];
    const float* b1 = (const float*)d_in[4];
    const float* W2 = (const float*)d_in[5];
    const float* b2 = (const float*)d_in[6];
    float* out = (float*)d_out;

    char* ws = (char*)d_ws;
    int*   counts = (int*)ws;                               // 32 B
    float* wgt    = (float*)(ws + 1024);                    // 16 KB
    int*   tlist  = (int*)(ws + 32768);                     // 128 KB
    unsigned short* xb   = (unsigned short*)(ws + 262144);  // 8.39 MB bf16
    unsigned short* hbuf = (unsigned short*)(ws + 8650752); // 33.55 MB bf16
    unsigned short* w1c  = (unsigned short*)(ws + 42205184);  // 67.1 MB bf16 native
    unsigned short* w2c  = (unsigned short*)(ws + 109314048); // 67.1 MB bf16 native
    // total workspace: 176,422,912 B

    hipMemsetAsync(counts, 0, NUM_EXPERTS * sizeof(int), stream);

    convgate_kernel<<<9216, 256, 0, stream>>>(x, Wg, bg, W1, W2,
                                              counts, tlist, wgt, xb, w1c, w2c);
    ffn1_kernel<<<dim3(D_HIDDEN / 256, MAXSLOT1), 512, 0, stream>>>(
        xb, w1c, b1, counts, tlist, hbuf);
    ffn2_kernel<<<dim3(D_MODEL / 128, MAXSLOT2), 256, 0, stream>>>(
        hbuf, w2c, b2, counts, tlist, wgt, out);
}

// Round 7
// 524.847 us; speedup vs baseline: 1.0919x; 1.0742x over previous
//
#include <hip/hip_runtime.h>
#include <stdint.h>

#define D_MODEL 1024
#define D_HIDDEN 4096
#define NUM_EXPERTS 8
#define NTOK 4096   // B*T = 2*2048
#define MAXSLOT1 24 // ffn1: sum_e ceil(cnt_e/256) <= 16+8
#define MAXSLOT2 40 // ffn2: sum_e ceil(cnt_e/128) <= 32+8

typedef __bf16 bf16x8 __attribute__((ext_vector_type(8)));
typedef float floatx4 __attribute__((ext_vector_type(4)));
typedef float f32x4v __attribute__((ext_vector_type(4)));   // clang vec for nontemporal
typedef unsigned int uint2e __attribute__((ext_vector_type(2)));
typedef unsigned int uint4e __attribute__((ext_vector_type(4)));

static __device__ __forceinline__ unsigned short f2bf(float f) {
    union { float f; unsigned int i; } v;
    v.f = f;
    unsigned int i = v.i;
    unsigned int r = (i + 0x7fffu + ((i >> 16) & 1u)) >> 16;  // RNE
    return (unsigned short)r;
}

// async global->LDS, 16B per lane. LDS dest operand is the WAVE-UNIFORM base;
// HW adds lane*16 B (m104/m108).
static __device__ __forceinline__ void gl_lds16(const unsigned short* g, unsigned short* l) {
    __builtin_amdgcn_global_load_lds(
        (const __attribute__((address_space(1))) void*)g,
        (__attribute__((address_space(3))) void*)l, 16, 0, 0);
}

// HW transpose read (verified in r3): lane with byte addr A receives column
// (A&127)>>3 of the 128-B-aligned [4k][16n] bf16 tile containing A (4 elems,
// k-ascending). offset:N is additive.
#define TRRD(dst, addr, off)                                   \
    asm volatile("ds_read_b64_tr_b16 %0, %1 offset:" #off      \
                 : "=v"(dst) : "v"(addr) : "memory")

static __device__ __forceinline__ bf16x8 pack_tr(uint2e a, uint2e b) {
    uint4e p; p.x = a.x; p.y = a.y; p.z = b.x; p.w = b.y;
    return __builtin_bit_cast(bf16x8, p);
}

// ---------------------------------------------------------------------------
// Fused: blocks 0..1023 = gating (one wave/token, launches FIRST so its
// latency-bound Wg gathers hide under the convert stream); blocks
// 1024..9215 = weight fp32->bf16 convert (native layout, nontemporal reads).
// ---------------------------------------------------------------------------
__global__ __launch_bounds__(256) void convgate_kernel(
    const float* __restrict__ x,
    const float* __restrict__ Wg,
    const float* __restrict__ bg,
    const float* __restrict__ W1,
    const float* __restrict__ W2,
    int* __restrict__ counts,
    int* __restrict__ tlist,
    float* __restrict__ wgt,
    unsigned short* __restrict__ xb,
    unsigned short* __restrict__ w1c,  // [E][D_MODEL][D_HIDDEN] bf16 native
    unsigned short* __restrict__ w2c)  // [E][D_HIDDEN][D_MODEL] bf16 native
{
    const int tid = threadIdx.x;
    if (blockIdx.x >= 1024) {
        const int bid = blockIdx.x - 1024;
        const int half = bid >> 12;  // 0: W1, 1: W2
        const float* src = half ? W2 : W1;
        unsigned short* dst = half ? w2c : w1c;
        const size_t c0 = ((size_t)(bid & 4095) * 256 + tid) * 8;
        f32x4v v[8];
#pragma unroll
        for (int q = 0; q < 4; ++q) {
            const f32x4v* s = (const f32x4v*)(src + c0 + (size_t)q * 8388608);
            v[q * 2]     = __builtin_nontemporal_load(s);
            v[q * 2 + 1] = __builtin_nontemporal_load(s + 1);
        }
#pragma unroll
        for (int q = 0; q < 4; ++q) {
            uint4 o;
            o.x = (unsigned)f2bf(v[q*2].x)   | ((unsigned)f2bf(v[q*2].y) << 16);
            o.y = (unsigned)f2bf(v[q*2].z)   | ((unsigned)f2bf(v[q*2].w) << 16);
            o.z = (unsigned)f2bf(v[q*2+1].x) | ((unsigned)f2bf(v[q*2+1].y) << 16);
            o.w = (unsigned)f2bf(v[q*2+1].z) | ((unsigned)f2bf(v[q*2+1].w) << 16);
            *(uint4*)(dst + c0 + (size_t)q * 8388608) = o;
        }
        return;
    }

    const int wave = tid >> 6;
    const int lane = tid & 63;
    const int tok = blockIdx.x * 4 + wave;

    float acc[NUM_EXPERTS];
#pragma unroll
    for (int e = 0; e < NUM_EXPERTS; e++) acc[e] = 0.f;

    const float4* xr = (const float4*)(x + (size_t)tok * D_MODEL);
    unsigned int* xbr = (unsigned int*)(xb + (size_t)tok * D_MODEL);

#pragma unroll
    for (int i = 0; i < 4; i++) {
        int d4 = i * 64 + lane;
        float4 v = xr[d4];
        unsigned int p0 = (unsigned int)f2bf(v.x) | ((unsigned int)f2bf(v.y) << 16);
        unsigned int p1 = (unsigned int)f2bf(v.z) | ((unsigned int)f2bf(v.w) << 16);
        uint2 pk; pk.x = p0; pk.y = p1;
        *(uint2*)&xbr[d4 * 2] = pk;

        float vc[4] = {v.x, v.y, v.z, v.w};
#pragma unroll
        for (int c = 0; c < 4; c++) {
            const float4* wr = (const float4*)(Wg + (size_t)(d4 * 4 + c) * NUM_EXPERTS);
            float4 w0 = wr[0], w1 = wr[1];
            acc[0] += vc[c] * w0.x; acc[1] += vc[c] * w0.y;
            acc[2] += vc[c] * w0.z; acc[3] += vc[c] * w0.w;
            acc[4] += vc[c] * w1.x; acc[5] += vc[c] * w1.y;
            acc[6] += vc[c] * w1.z; acc[7] += vc[c] * w1.w;
        }
    }
#pragma unroll
    for (int e = 0; e < NUM_EXPERTS; e++) {
        float v = acc[e];
#pragma unroll
        for (int off = 32; off > 0; off >>= 1) v += __shfl_xor(v, off, 64);
        acc[e] = v;
    }
    if (lane == 0) {
        float lg[NUM_EXPERTS];
#pragma unroll
        for (int e = 0; e < NUM_EXPERTS; e++) lg[e] = acc[e] + bg[e];
        int amax = 0;
        float m = lg[0];
#pragma unroll
        for (int e = 1; e < NUM_EXPERTS; e++) {
            if (lg[e] > m) { m = lg[e]; amax = e; }  // first-index-wins
        }
        float s = 0.f;
#pragma unroll
        for (int e = 0; e < NUM_EXPERTS; e++) s += __expf(lg[e] - m);
        wgt[tok] = 1.0f / s;
        int pos = atomicAdd(&counts[amax], 1);
        tlist[amax * NTOK + pos] = tok;
    }
}

// ---------------------------------------------------------------------------
// tile-slot -> (expert, m_tile, count); tile = 1<<shift rows.
// ---------------------------------------------------------------------------
__device__ __forceinline__ bool slot_to_expert(const int* counts, int slot, int shift,
                                               int& e_out, int& mt_out, int& cnt_out) {
    int cum = 0;
    for (int i = 0; i < NUM_EXPERTS; i++) {
        int c = counts[i];
        int tt = (c + (1 << shift) - 1) >> shift;
        if (slot < cum + tt) {
            e_out = i; mt_out = slot - cum; cnt_out = c;
            return true;
        }
        cum += tt;
    }
    return false;
}

// ---------------------------------------------------------------------------
// FFN1: 256x256 tile, BK=64, 8 waves (2M x 4N). r5-proven sync skeleton
// (STAGE next -> COMPUTE cur -> __syncthreads). Unchanged this round.
// ---------------------------------------------------------------------------
__global__ __launch_bounds__(512, 2) void ffn1_kernel(
    const unsigned short* __restrict__ xb,
    const unsigned short* __restrict__ w1c,
    const float* __restrict__ b1,
    const int* __restrict__ counts,
    const int* __restrict__ tlist,
    unsigned short* __restrict__ h)
{
    int e, mt, cnt;
    if (!slot_to_expert(counts, blockIdx.y, 8, e, mt, cnt)) return;
    const int n0 = blockIdx.x * 256;

    __shared__ __align__(16) unsigned short Al[2][256 * 64];
    __shared__ __align__(16) unsigned short Bl[2][256 * 64];
    __shared__ int toks[256];

    const int tid = threadIdx.x;
    if (tid < 256) {
        int r = mt * 256 + tid;
        toks[tid] = (r < cnt) ? tlist[e * NTOK + r] : -1;
    }
    __syncthreads();

    const int wave = tid >> 6, lane = tid & 63;
    const int quad = lane >> 4, lm = lane & 15;
    const int mo = (wave >> 2) * 128, wc = wave & 3;
    const int no = wc * 64;

    const unsigned short* w1e = w1c + (size_t)e * D_MODEL * D_HIDDEN;
    const int ag = ((tid & 7) ^ ((tid >> 3) & 7)) * 8;  // pre-swizzled A granule
    const unsigned short* asrc[4];
#pragma unroll
    for (int j = 0; j < 4; ++j) {
        int m = j * 64 + (tid >> 3);
        int tk = toks[m];
        asrc[j] = xb + (size_t)(tk < 0 ? 0 : tk) * D_MODEL + ag;
    }
    const int bk = (tid >> 1) & 63, bn8 = (tid & 1) * 8;
    const unsigned short* bsrc[4];
#pragma unroll
    for (int j = 0; j < 4; ++j) {
        int nb = j * 4 + (tid >> 7);
        bsrc[j] = w1e + (size_t)bk * D_HIDDEN + n0 + nb * 16 + bn8;
    }

#define F1_STAGE(p, k0)                                                  \
    do {                                                                 \
        _Pragma("unroll")                                                \
        for (int j = 0; j < 4; ++j)                                      \
            gl_lds16(asrc[j] + (k0), &Al[p][j * 4096 + wave * 512]);     \
        _Pragma("unroll")                                                \
        for (int j = 0; j < 4; ++j)                                      \
            gl_lds16(bsrc[j] + (size_t)(k0) * D_HIDDEN,                  \
                     &Bl[p][j * 4096 + wave * 512]);                     \
    } while (0)

#define F1_COMPUTE(p)                                                         \
    do {                                                                      \
        const unsigned short* Ab = &Al[p][0];                                 \
        const unsigned bvB = (unsigned)(uintptr_t)&Bl[p][0]                   \
                           + (unsigned)(wc * 8192 + quad * 256 + lm * 8);     \
        _Pragma("unroll")                                                     \
        for (int s = 0; s < 2; ++s) {                                         \
            bf16x8 af[8];                                                     \
            const int gsw = ((s * 4 + quad) ^ (lm & 7)) * 8;                  \
            _Pragma("unroll")                                                 \
            for (int i = 0; i < 8; ++i)                                       \
                af[i] = *(const bf16x8*)(Ab + (mo + i * 16 + lm) * 64 + gsw); \
            uint2e t0, t1, t2, t3, t4, t5, t6, t7;                            \
            const unsigned vs = bvB + s * 1024;                               \
            unsigned v0 = vs, v1 = vs + 2048, v2 = vs + 4096, v3 = vs + 6144; \
            TRRD(t0, v0, 0); TRRD(t1, v0, 128);                               \
            TRRD(t2, v1, 0); TRRD(t3, v1, 128);                               \
            TRRD(t4, v2, 0); TRRD(t5, v2, 128);                               \
            TRRD(t6, v3, 0); TRRD(t7, v3, 128);                               \
            asm volatile("s_waitcnt lgkmcnt(0)" ::: "memory");                \
            __builtin_amdgcn_sched_barrier(0);                                \
            bf16x8 bf[4];                                                     \
            bf[0] = pack_tr(t0, t1); bf[1] = pack_tr(t2, t3);                 \
            bf[2] = pack_tr(t4, t5); bf[3] = pack_tr(t6, t7);                 \
            _Pragma("unroll")                                                 \
            for (int i = 0; i < 8; ++i)                                       \
                _Pragma("unroll")                                             \
                for (int j = 0; j < 4; ++j)                                   \
                    acc[i][j] = __builtin_amdgcn_mfma_f32_16x16x32_bf16(      \
                        af[i], bf[j], acc[i][j], 0, 0, 0);                    \
        }                                                                     \
    } while (0)

    floatx4 acc[8][4];
#pragma unroll
    for (int i = 0; i < 8; i++)
#pragma unroll
        for (int j = 0; j < 4; j++) acc[i][j] = (floatx4){0.f, 0.f, 0.f, 0.f};

    const int NT = D_MODEL / 64;  // 16
    F1_STAGE(0, 0);
    __syncthreads();
    int cur = 0;
    for (int kt = 1; kt < NT; ++kt) {
        F1_STAGE(cur ^ 1, kt * 64);
        F1_COMPUTE(cur);
        __syncthreads();
        cur ^= 1;
    }
    F1_COMPUTE(cur);

    const float* b1e = b1 + (size_t)e * D_HIDDEN;
#pragma unroll
    for (int ni = 0; ni < 4; ++ni) {
        int n = n0 + no + ni * 16 + lm;
        float bias = b1e[n];
#pragma unroll
        for (int mi = 0; mi < 8; ++mi)
#pragma unroll
            for (int r = 0; r < 4; ++r) {
                int m = mo + mi * 16 + quad * 4 + r;
                int tk = toks[m];
                if (tk >= 0) {
                    float z = acc[mi][ni][r] + bias;
                    h[(size_t)tk * D_HIDDEN + n] = f2bf(z / (1.f + __expf(-z)));
                }
            }
    }
}

// ---------------------------------------------------------------------------
// FFN2: 128x128 tile, BK=64, 4 waves (2M x 2N), K=4096 (NT=64).
// Counted-vmcnt raw-barrier pipeline (T3/T4), prefetch depth 2.
// Per-wave STAGE = 8 gl_lds; steady state waits vmcnt(8) (tile k landed),
// never drains mid-loop. sched_barrier(0) fences every barrier crossing.
// LDS 64.5 KB -> 2 blocks/CU. No split-K, no atomics.
// ---------------------------------------------------------------------------
__global__ __launch_bounds__(256, 2) void ffn2_kernel(
    const unsigned short* __restrict__ h,
    const unsigned short* __restrict__ w2c,
    const float* __restrict__ b2,
    const int* __restrict__ counts,
    const int* __restrict__ tlist,
    const float* __restrict__ wgt,
    float* __restrict__ out)
{
    int e, mt, cnt;
    if (!slot_to_expert(counts, blockIdx.y, 7, e, mt, cnt)) return;
    const int n0 = blockIdx.x * 128;

    __shared__ __align__(16) unsigned short Al[2][128 * 64];
    __shared__ __align__(16) unsigned short Bl[2][128 * 64];
    __shared__ int toks[128];

    const int tid = threadIdx.x;
    if (tid < 128) {
        int r = mt * 128 + tid;
        toks[tid] = (r < cnt) ? tlist[e * NTOK + r] : -1;
    }
    __syncthreads();

    const int wave = tid >> 6, lane = tid & 63;
    const int quad = lane >> 4, lm = lane & 15;
    const int mo = (wave & 1) * 64, wc = wave >> 1;
    const int no = wc * 64;

    const unsigned short* w2e = w2c + (size_t)e * D_MODEL * D_HIDDEN;
    const int ag = ((tid & 7) ^ ((tid >> 3) & 7)) * 8;
    const unsigned short* asrc[4];
#pragma unroll
    for (int j = 0; j < 4; ++j) {
        int m = j * 32 + (tid >> 3);
        int tk = toks[m];
        asrc[j] = h + (size_t)(tk < 0 ? 0 : tk) * D_HIDDEN + ag;
    }
    const int bk = (tid >> 1) & 63, bn8 = (tid & 1) * 8;
    const unsigned short* bsrc[4];
#pragma unroll
    for (int j = 0; j < 4; ++j) {
        int nb = j * 2 + (tid >> 7);
        bsrc[j] = w2e + (size_t)bk * D_MODEL + n0 + nb * 16 + bn8;
    }

#define F2_STAGE(p, k0)                                                  \
    do {                                                                 \
        _Pragma("unroll")                                                \
        for (int j = 0; j < 4; ++j)                                      \
            gl_lds16(asrc[j] + (k0), &Al[p][j * 2048 + wave * 512]);     \
        _Pragma("unroll")                                                \
        for (int j = 0; j < 4; ++j)                                      \
            gl_lds16(bsrc[j] + (size_t)(k0) * D_MODEL,                   \
                     &Bl[p][j * 2048 + wave * 512]);                     \
    } while (0)

#define F2_COMPUTE(p)                                                         \
    do {                                                                      \
        const unsigned short* Ab = &Al[p][0];                                 \
        const unsigned bvB = (unsigned)(uintptr_t)&Bl[p][0]                   \
                           + (unsigned)(wc * 8192 + quad * 256 + lm * 8);     \
        _Pragma("unroll")                                                     \
        for (int s = 0; s < 2; ++s) {                                         \
            bf16x8 af[4];                                                     \
            const int gsw = ((s * 4 + quad) ^ (lm & 7)) * 8;                  \
            _Pragma("unroll")                                                 \
            for (int i = 0; i < 4; ++i)                                       \
                af[i] = *(const bf16x8*)(Ab + (mo + i * 16 + lm) * 64 + gsw); \
            uint2e t0, t1, t2, t3, t4, t5, t6, t7;                            \
            const unsigned vs = bvB + s * 1024;                               \
            unsigned v0 = vs, v1 = vs + 2048, v2 = vs + 4096, v3 = vs + 6144; \
            TRRD(t0, v0, 0); TRRD(t1, v0, 128);                               \
            TRRD(t2, v1, 0); TRRD(t3, v1, 128);                               \
            TRRD(t4, v2, 0); TRRD(t5, v2, 128);                               \
            TRRD(t6, v3, 0); TRRD(t7, v3, 128);                               \
            asm volatile("s_waitcnt lgkmcnt(0)" ::: "memory");                \
            __builtin_amdgcn_sched_barrier(0);                                \
            bf16x8 bf[4];                                                     \
            bf[0] = pack_tr(t0, t1); bf[1] = pack_tr(t2, t3);                 \
            bf[2] = pack_tr(t4, t5); bf[3] = pack_tr(t6, t7);                 \
            _Pragma("unroll")                                                 \
            for (int i = 0; i < 4; ++i)                                       \
                _Pragma("unroll")                                             \
                for (int j = 0; j < 4; ++j)                                   \
                    acc[i][j] = __builtin_amdgcn_mfma_f32_16x16x32_bf16(      \
                        af[i], bf[j], acc[i][j], 0, 0, 0);                    \
        }                                                                     \
    } while (0)

    floatx4 acc[4][4];
#pragma unroll
    for (int i = 0; i < 4; i++)
#pragma unroll
        for (int j = 0; j < 4; j++) acc[i][j] = (floatx4){0.f, 0.f, 0.f, 0.f};

    const int NT = D_HIDDEN / 64;  // 64
    F2_STAGE(0, 0);
    F2_STAGE(1, 64);

    for (int kt = 0; kt < NT; ++kt) {
        const int p = kt & 1;
        // wait: this wave's tile-kt loads (oldest 8) have landed; barrier
        // makes that true for ALL waves' portions of tile kt.
        if (kt + 1 < NT) asm volatile("s_waitcnt vmcnt(8)" ::: "memory");
        else             asm volatile("s_waitcnt vmcnt(0)" ::: "memory");
        __builtin_amdgcn_s_barrier();
        __builtin_amdgcn_sched_barrier(0);
        F2_COMPUTE(p);
        if (kt + 1 < NT) {
            __builtin_amdgcn_sched_barrier(0);
            __builtin_amdgcn_s_barrier();   // all waves' reads of buf p retired
            __builtin_amdgcn_sched_barrier(0);
            if (kt + 2 < NT) F2_STAGE(p, (kt + 2) * 64);
        }
    }

    const float* b2e = b2 + (size_t)e * D_MODEL;
#pragma unroll
    for (int ni = 0; ni < 4; ++ni) {
        int n = n0 + no + ni * 16 + lm;
        float bias = b2e[n];
#pragma unroll
        for (int mi = 0; mi < 4; ++mi)
#pragma unroll
            for (int r = 0; r < 4; ++r) {
                int m = mo + mi * 16 + quad * 4 + r;
                int tk = toks[m];
                if (tk >= 0) {
                    out[(size_t)tk * D_MODEL + n] = (acc[mi][ni][r] + bias) * wgt[tk];
                }
            }
    }
}

// ---------------------------------------------------------------------------
extern "C" void kernel_launch(void* const* d_in, const int* in_sizes, int n_in,
                              void* d_out, int out_size, void* d_ws, size_t ws_size,
                              hipStream_t stream) {
    const float* x  = (const float*)d_in[0];
    const float* Wg = (const float*)d_in[1];
    const float* bg = (const float*)d_in[2];
    const float* W1 = (const float*)d_in[3];
    const float* b1 = (const float*)d_in[4];
    const float* W2 = (const float*)d_in[5];
    const float* b2 = (const float*)d_in[6];
    float* out = (float*)d_out;

    char* ws = (char*)d_ws;
    int*   counts = (int*)ws;                               // 32 B
    float* wgt    = (float*)(ws + 1024);                    // 16 KB
    int*   tlist  = (int*)(ws + 32768);                     // 128 KB
    unsigned short* xb   = (unsigned short*)(ws + 262144);  // 8.39 MB bf16
    unsigned short* hbuf = (unsigned short*)(ws + 8650752); // 33.55 MB bf16
    unsigned short* w1c  = (unsigned short*)(ws + 42205184);  // 67.1 MB bf16 native
    unsigned short* w2c  = (unsigned short*)(ws + 109314048); // 67.1 MB bf16 native
    // total workspace: 176,422,912 B

    (void)hipMemsetAsync(counts, 0, NUM_EXPERTS * sizeof(int), stream);

    convgate_kernel<<<9216, 256, 0, stream>>>(x, Wg, bg, W1, W2,
                                              counts, tlist, wgt, xb, w1c, w2c);
    ffn1_kernel<<<dim3(D_HIDDEN / 256, MAXSLOT1), 512, 0, stream>>>(
        xb, w1c, b1, counts, tlist, hbuf);
    ffn2_kernel<<<dim3(D_MODEL / 128, MAXSLOT2), 256, 0, stream>>>(
        hbuf, w2c, b2, counts, tlist, wgt, out);
}